// Round 2
// 481.730 us; speedup vs baseline: 2.3991x; 2.3991x over previous
//
#include <hip/hip_runtime.h>

// out[o,c,y,x] = sum_{i,j<31} s[c,y+i-15,x+j-15] * w[o,c,i,j] + bias[c]
// via v_mfma_f32_16x16x32_f16:
//   per (i, x):  C[m=o, n=dy] += A[m][k] * B[k][n]
//   A[m][k] = w[m&7, c, i, k]          (k = j, j=31 zero-padded)
//   B[k][n] = s[y0+n+i-15, x+k-15]
// Each wave owns 16 consecutive x; acc[16] f32x4 accumulates over i in-register.
// B-frags for the wave's 16 x at one (i,kg) all come from a single 12-dword
// window -> 3x ds_read_b128 + 11 v_alignbit builds all 16 fragments.

typedef _Float16 f16x8 __attribute__((ext_vector_type(8)));
typedef float    f32x4 __attribute__((ext_vector_type(4)));

#define TY   16          // output rows per block (= MFMA N)
#define TXB  64          // output cols per block (16 per wave)
#define SR   46          // signal tile rows = TY + 30
#define SDW  48          // used dwords per row (96 f16 elems)
#define SROW 52          // row stride in dwords (mult of 4 -> 16B-aligned b128 reads)

__device__ unsigned int g_wpk[8 * 8 * 31 * 16];  // [c][o][i][16 dw] f16 pairs, j=31 -> 0

__global__ void wpack(const float* __restrict__ wgt) {
  int t = blockIdx.x * 256 + threadIdx.x;
  if (t >= 8 * 8 * 31) return;
  const int i = t % 31;
  const int o = (t / 31) & 7;
  const int c = t / 248;
  const float* src = wgt + (((o * 8) + c) * 31 + i) * 31;
  unsigned int* dst = g_wpk + (((c * 8) + o) * 31 + i) * 16;
  #pragma unroll
  for (int d = 0; d < 16; ++d) {
    float w0 = src[2 * d];
    float w1 = (2 * d + 1 < 31) ? src[2 * d + 1] : 0.f;
    union { _Float16 h[2]; unsigned int u; } p;
    p.h[0] = (_Float16)w0; p.h[1] = (_Float16)w1;
    dst[d] = p.u;
  }
}

__global__ __launch_bounds__(256, 4)
void conv_mfma(const float* __restrict__ sig,
               const float* __restrict__ bias,
               float* __restrict__ out) {
  __shared__ __align__(16) unsigned int ldss[SR * SROW];   // f16-pair packed signal
  __shared__ __align__(16) unsigned int ldsw[8 * 31 * 16]; // f16-pair packed weights

  const int tid = threadIdx.x;
  const int c  = blockIdx.z;
  const int x0 = blockIdx.x * TXB;
  const int y0 = blockIdx.y * TY;

  // ---- stage signal tile: rows y0-15 .. y0+30, cols x0-15 .. x0+80 (96 elems) ----
  const float* sc = sig + c * (1024 * 1024);
  for (int f = tid; f < SR * SDW; f += 256) {
    const int r = f / SDW;
    const int d = f - r * SDW;
    const int gy = y0 + r - 15;
    const int gx = x0 + 2 * d - 15;
    float s0 = 0.f, s1 = 0.f;
    if ((unsigned)gy < 1024u) {
      const float* srcr = sc + gy * 1024;
      if ((unsigned)gx < 1024u)       s0 = srcr[gx];
      if ((unsigned)(gx + 1) < 1024u) s1 = srcr[gx + 1];
    }
    union { _Float16 h[2]; unsigned int u; } p;
    p.h[0] = (_Float16)s0; p.h[1] = (_Float16)s1;
    ldss[r * SROW + d] = p.u;
  }
  // ---- stage weights for this c ----
  for (int f = tid; f < 8 * 31 * 16; f += 256) ldsw[f] = g_wpk[c * (8 * 31 * 16) + f];
  __syncthreads();

  const int lane = tid & 63;
  const int wv   = tid >> 6;        // wave 0..3
  const int n    = lane & 15;       // MFMA col (B,D: n) -> y offset
  const int kg   = lane >> 4;       // k-group 0..3 (k = kg*8 + e)
  const int xw   = wv * 16;         // wave's x base within block

  f32x4 acc[16];
  #pragma unroll
  for (int xi = 0; xi < 16; ++xi) acc[xi] = (f32x4){0.f, 0.f, 0.f, 0.f};

  const unsigned int* wbase = &ldsw[(lane & 7) * 31 * 16 + kg * 4];

  for (int i = 0; i < 31; ++i) {
    // A fragment: w[o = lane&7][i][k = kg*8 .. +8]  (16B aligned ds_read_b128)
    union { uint4 v; f16x8 h; } au;
    au.v = *(const uint4*)(wbase + i * 16);
    const f16x8 af = au.h;

    // B window: 12 dwords = elements [xw + 8kg .. xw + 8kg + 23] of tile row n+i
    const unsigned int* rowp = &ldss[(n + i) * SROW + 4 * kg + 8 * wv];
    const uint4 R0 = *(const uint4*)(rowp);
    const uint4 R1 = *(const uint4*)(rowp + 4);
    const uint4 R2 = *(const uint4*)(rowp + 8);
    const unsigned int W[12] = {R0.x, R0.y, R0.z, R0.w,
                                R1.x, R1.y, R1.z, R1.w,
                                R2.x, R2.y, R2.z, R2.w};
    // shifted-by-1-element dwords: A_[d] = (elem 2d+1, elem 2d+2)
    unsigned int A_[11];
    #pragma unroll
    for (int d = 0; d < 11; ++d)
      A_[d] = __builtin_amdgcn_alignbit(W[d + 1], W[d], 16);

    #pragma unroll
    for (int xg = 0; xg < 4; ++xg) {
      const int d0 = 2 * xg;
      union { unsigned int u[4]; f16x8 h; } b0, b1, b2, b3;
      b0.u[0] = W[d0];      b0.u[1] = W[d0 + 1];  b0.u[2] = W[d0 + 2];  b0.u[3] = W[d0 + 3];
      b1.u[0] = A_[d0];     b1.u[1] = A_[d0 + 1]; b1.u[2] = A_[d0 + 2]; b1.u[3] = A_[d0 + 3];
      b2.u[0] = W[d0 + 1];  b2.u[1] = W[d0 + 2];  b2.u[2] = W[d0 + 3];  b2.u[3] = W[d0 + 4];
      b3.u[0] = A_[d0 + 1]; b3.u[1] = A_[d0 + 2]; b3.u[2] = A_[d0 + 3]; b3.u[3] = A_[d0 + 4];
      acc[4*xg+0] = __builtin_amdgcn_mfma_f32_16x16x32_f16(af, b0.h, acc[4*xg+0], 0, 0, 0);
      acc[4*xg+1] = __builtin_amdgcn_mfma_f32_16x16x32_f16(af, b1.h, acc[4*xg+1], 0, 0, 0);
      acc[4*xg+2] = __builtin_amdgcn_mfma_f32_16x16x32_f16(af, b2.h, acc[4*xg+2], 0, 0, 0);
      acc[4*xg+3] = __builtin_amdgcn_mfma_f32_16x16x32_f16(af, b3.h, acc[4*xg+3], 0, 0, 0);
    }
  }

  // C/D layout: col = lane&15 = n (y), row = (lane>>4)*4 + reg = o. Rows 8..15 are
  // duplicates of 0..7 (A rows repeat o mod 8) -> lanes 32..63 masked off.
  if (lane < 32) {
    const float bv = bias[c];
    const int y  = y0 + n;
    const int hi = lane >> 4;
    #pragma unroll
    for (int r = 0; r < 4; ++r) {
      const int o = hi * 4 + r;
      float* op = out + (((size_t)(o * 8 + c) * 1024 + y) * 1024 + x0 + xw);
      #pragma unroll
      for (int g = 0; g < 4; ++g) {
        float4 v;
        v.x = acc[4*g+0][r] + bv;
        v.y = acc[4*g+1][r] + bv;
        v.z = acc[4*g+2][r] + bv;
        v.w = acc[4*g+3][r] + bv;
        *(float4*)(op + 4*g) = v;
      }
    }
  }
}

extern "C" void kernel_launch(void* const* d_in, const int* in_sizes, int n_in,
                              void* d_out, int out_size, void* d_ws, size_t ws_size,
                              hipStream_t stream) {
  const float* sig  = (const float*)d_in[0];   // (1,8,1024,1024) fp32
  const float* wgt  = (const float*)d_in[1];   // (8,8,31,31) fp32
  const float* bias = (const float*)d_in[2];   // (8,) fp32
  float* out = (float*)d_out;                  // (8,8,1024,1024) fp32

  wpack<<<(8 * 8 * 31 + 255) / 256, 256, 0, stream>>>(wgt);
  dim3 grid(1024 / TXB, 1024 / TY, 8);
  conv_mfma<<<grid, 256, 0, stream>>>(sig, bias, out);
}

// Round 3
// 410.025 us; speedup vs baseline: 2.8187x; 1.1749x over previous
//
#include <hip/hip_runtime.h>

// out[o,c,y,x] = sum_{i,j<31} s[c,y+i-15,x+j-15] * w[o,c,i,j] + bias[c]
// via v_mfma_f32_16x16x32_f16 with the x-shift packed into m:
//   m = 8*s + o (s in {0,1}), n = y (16), k = j + s (32)
//   A[8s+o][k] = w[o,c,i,k-s]   (precomputed table, zero outside j-range)
//   B[k][n]    = s[y0+n+i-15, x0+xw+2xg+k-15]   (independent of s!)
// One MFMA yields out[o][y][xb] and out[o][y][xb+1] -> 8 MFMAs cover 16 x.
// All B fragments are even-shifted: consecutive dword quads of one 12-dword
// window -> 3x aligned ds_read_b128, no alignbit.
// Weights never touch LDS: A-frag table laid out so lane l reads byte l*16
// (one coalesced global_load_dwordx4 per i, L1-resident).

typedef _Float16 f16x8 __attribute__((ext_vector_type(8)));
typedef float    f32x4 __attribute__((ext_vector_type(4)));

#define TY   16          // output rows per block (= MFMA N)
#define TXB  64          // output cols per block (16 per wave)
#define SR   46          // signal tile rows = TY + 30
#define SDW  48          // used dwords per row (96 f16 elems)
#define SROW 52          // row stride dwords (mult of 4 -> aligned b128; 20 mod 32 banks)

// A-fragment table: [c][i][kg][m][4dw] f16-pairs; lane l of wave reads dword (c*31+i)*256 + l*4
__device__ unsigned int g_wA[8 * 31 * 256];

__global__ void wpack(const float* __restrict__ wgt) {
  int t = blockIdx.x * 256 + threadIdx.x;
  if (t >= 8 * 31 * 256) return;
  const int d  = t & 3;
  const int m  = (t >> 2) & 15;
  const int kg = (t >> 6) & 3;
  const int r  = t >> 8;
  const int i  = r % 31;
  const int c  = r / 31;
  const int o  = m & 7;
  const int s  = m >> 3;
  const int k0 = kg * 8 + 2 * d;
  const int j0 = k0 - s, j1 = k0 + 1 - s;
  const float* wsrc = wgt + ((o * 8 + c) * 31 + i) * 31;
  const float w0 = ((unsigned)j0 < 31u) ? wsrc[j0] : 0.f;
  const float w1 = ((unsigned)j1 < 31u) ? wsrc[j1] : 0.f;
  union { _Float16 h[2]; unsigned int u; } p;
  p.h[0] = (_Float16)w0; p.h[1] = (_Float16)w1;
  g_wA[t] = p.u;
}

__global__ __launch_bounds__(256, 4)
void conv_mfma2(const float* __restrict__ sig,
                const float* __restrict__ bias,
                float* __restrict__ out) {
  __shared__ __align__(16) unsigned int ldss[SR * SROW];   // 9.4 KB, signal only

  const int tid = threadIdx.x;
  const int c  = blockIdx.z;
  const int x0 = blockIdx.x * TXB;
  const int y0 = blockIdx.y * TY;

  // ---- stage signal tile: rows y0-15 .. y0+30, cols x0-15 .. x0+80 ----
  const float* sc = sig + c * (1024 * 1024);
  for (int f = tid; f < SR * SDW; f += 256) {
    const int r = f / SDW;
    const int d = f - r * SDW;
    const int gy = y0 + r - 15;
    const int gx = x0 + 2 * d - 15;
    float s0 = 0.f, s1 = 0.f;
    if ((unsigned)gy < 1024u) {
      const float* srcr = sc + gy * 1024;
      if ((unsigned)gx < 1024u)       s0 = srcr[gx];
      if ((unsigned)(gx + 1) < 1024u) s1 = srcr[gx + 1];
    }
    union { _Float16 h[2]; unsigned int u; } p;
    p.h[0] = (_Float16)s0; p.h[1] = (_Float16)s1;
    ldss[r * SROW + d] = p.u;
  }
  __syncthreads();

  const int lane = tid & 63;
  const int wv   = tid >> 6;        // wave 0..3
  const int n    = lane & 15;       // MFMA col (B,D) -> y offset
  const int kg   = lane >> 4;       // k-group 0..3
  const int xw   = wv * 16;         // wave's x base within block

  f32x4 acc[8];
  #pragma unroll
  for (int xg = 0; xg < 8; ++xg) acc[xg] = (f32x4){0.f, 0.f, 0.f, 0.f};

  const uint4* wq = (const uint4*)g_wA + c * (31 * 64) + lane;
  uint4 wnext = wq[0];

  for (int i = 0; i < 31; ++i) {
    union { uint4 v; f16x8 h; } au;
    au.v = wnext;
    if (i < 30) wnext = wq[(i + 1) * 64];

    // B window: 12 dwords = tile elements [16wv+8kg .. +23] of row n+i
    const unsigned int* rowp = &ldss[(n + i) * SROW + 8 * wv + 4 * kg];
    const uint4 R0 = *(const uint4*)(rowp);
    const uint4 R1 = *(const uint4*)(rowp + 4);
    const uint4 R2 = *(const uint4*)(rowp + 8);
    const unsigned int W[12] = {R0.x, R0.y, R0.z, R0.w,
                                R1.x, R1.y, R1.z, R1.w,
                                R2.x, R2.y, R2.z, R2.w};
    #pragma unroll
    for (int xg = 0; xg < 8; ++xg) {
      union { unsigned int u[4]; f16x8 h; } b;
      b.u[0] = W[xg]; b.u[1] = W[xg + 1]; b.u[2] = W[xg + 2]; b.u[3] = W[xg + 3];
      acc[xg] = __builtin_amdgcn_mfma_f32_16x16x32_f16(au.h, b.h, acc[xg], 0, 0, 0);
    }
  }

  // ---- epilogue ----
  // C/D: col = lane&15 = y, row m = 4*kg + reg. m = 8s + o: s = x parity, o = out ch.
  // kg 0,1 hold s=0 (even x), kg 2,3 hold s=1 (odd x); partner lane = lane^32.
  // o = (kg&1)*4 + reg. Lane stores x half h = kg>>1 (xg 4h..4h+3) as 2 float4.
  const float bv  = bias[c];
  const int  h    = kg >> 1;
  const int  olo  = (kg & 1) * 4;
  const int  y    = y0 + n;
  const bool low  = (kg < 2);

  #pragma unroll
  for (int r = 0; r < 4; ++r) {
    float av[8], pv[8];
    #pragma unroll
    for (int xg = 0; xg < 8; ++xg) {
      av[xg] = acc[xg][r] + bv;
      pv[xg] = __shfl_xor(av[xg], 32);
    }
    const int o = olo + r;
    float* op = out + (((size_t)(o * 8 + c) * 1024 + y) * 1024 + x0 + xw + 8 * h);
    float4 v0, v1;
    if (h == 0) {
      v0.x = low ? av[0] : pv[0]; v0.y = low ? pv[0] : av[0];
      v0.z = low ? av[1] : pv[1]; v0.w = low ? pv[1] : av[1];
      v1.x = low ? av[2] : pv[2]; v1.y = low ? pv[2] : av[2];
      v1.z = low ? av[3] : pv[3]; v1.w = low ? pv[3] : av[3];
    } else {
      v0.x = low ? av[4] : pv[4]; v0.y = low ? pv[4] : av[4];
      v0.z = low ? av[5] : pv[5]; v0.w = low ? pv[5] : av[5];
      v1.x = low ? av[6] : pv[6]; v1.y = low ? pv[6] : av[6];
      v1.z = low ? av[7] : pv[7]; v1.w = low ? pv[7] : av[7];
    }
    *(float4*)(op)     = v0;
    *(float4*)(op + 4) = v1;
  }
}

extern "C" void kernel_launch(void* const* d_in, const int* in_sizes, int n_in,
                              void* d_out, int out_size, void* d_ws, size_t ws_size,
                              hipStream_t stream) {
  const float* sig  = (const float*)d_in[0];   // (1,8,1024,1024) fp32
  const float* wgt  = (const float*)d_in[1];   // (8,8,31,31) fp32
  const float* bias = (const float*)d_in[2];   // (8,) fp32
  float* out = (float*)d_out;                  // (8,8,1024,1024) fp32

  wpack<<<(8 * 31 * 256 + 255) / 256, 256, 0, stream>>>(wgt);
  dim3 grid(1024 / TXB, 1024 / TY, 8);
  conv_mfma2<<<grid, 256, 0, stream>>>(sig, bias, out);
}

// Round 4
// 397.855 us; speedup vs baseline: 2.9049x; 1.0306x over previous
//
#include <hip/hip_runtime.h>

// out[o,c,y,x] = sum_{i',j<31} s[c,y+i'-15,x+j-15] * w[o,c,i',j] + bias[c]
// via v_mfma_f32_16x16x32_f16 with the Y-shift packed into m:
//   m = 8*s + o (s in {0,1}), n = x (16 cols), k = j (32, j=31 zero-pad)
//   A_i[8s+o][k] = w[o,c,i-s,k]  (i = i'+s, loop i = 0..31; zero outside range)
//   B_i,p[k][n]  = s[y0+2p+i-15, x0+xw+n+k-15]   -- ONE signal row, wave-uniform
// Lane (n,kg) B-fragment = 8 consecutive f16 at column E = xw+n+8kg of that row
// -> dual-parity LDS copies make it 4 aligned dwords for any E.
// Rows recur across i (row = i+2p): 16-slot register cache, one new row/iter.

typedef _Float16 f16x8 __attribute__((ext_vector_type(8)));
typedef float    f32x4 __attribute__((ext_vector_type(4)));

#define TY   16          // output rows per block
#define TXB  64          // output cols per block (16 per wave)
#define SR   48          // 46 real tile rows + 2 garbage rows (unguarded prefetch)
#define SDW  48          // dwords per parity copy per row (96 f16)
#define SROW 97          // row stride dwords: [copy0 48][copy1 48][pad 1]

// A-fragment table: [c][i][lane][4dw]; lane l reads 16B at byte l*16 (coalesced)
__device__ unsigned int g_wA[8 * 32 * 64 * 4];

__global__ void wpack(const float* __restrict__ wgt) {
  int t = blockIdx.x * 256 + threadIdx.x;
  if (t >= 8 * 32 * 64 * 4) return;
  const int d    = t & 3;
  const int lane = (t >> 2) & 63;
  const int i    = (t >> 8) & 31;
  const int c    = t >> 13;
  const int m  = lane & 15;
  const int kg = lane >> 4;
  const int o  = m & 7;
  const int s  = m >> 3;
  const int ip = i - s;                 // weight row i' = i - s
  const int k0 = kg * 8 + 2 * d;        // k = j
  float w0 = 0.f, w1 = 0.f;
  if ((unsigned)ip < 31u) {
    const float* wsrc = wgt + ((o * 8 + c) * 31 + ip) * 31;
    if (k0 < 31)     w0 = wsrc[k0];
    if (k0 + 1 < 31) w1 = wsrc[k0 + 1];
  }
  union { _Float16 h[2]; unsigned int u; } p;
  p.h[0] = (_Float16)w0; p.h[1] = (_Float16)w1;
  g_wA[t] = p.u;
}

__global__ __launch_bounds__(256, 4)
void conv_mfma3(const float* __restrict__ sig,
                const float* __restrict__ bias,
                float* __restrict__ out) {
  __shared__ unsigned int ldss[SR * SROW];   // 18.6 KB

  const int tid = threadIdx.x;
  const int c  = blockIdx.z;
  const int x0 = blockIdx.x * TXB;
  const int y0 = blockIdx.y * TY;

  // ---- stage tile: rows y0-15..y0+30 (46), elements x0-15..x0+80, dual parity ----
  const float* sc = sig + c * (1024 * 1024);
  for (int f = tid; f < 46 * SDW; f += 256) {
    const int r = f / SDW;
    const int d = f - r * SDW;
    const int gy = y0 + r - 15;
    const int gx = x0 + 2 * d - 15;
    float s0 = 0.f, s1 = 0.f, s2 = 0.f;
    if ((unsigned)gy < 1024u) {
      const float* srcr = sc + gy * 1024;
      if ((unsigned)gx < 1024u)       s0 = srcr[gx];
      if ((unsigned)(gx + 1) < 1024u) s1 = srcr[gx + 1];
      if ((unsigned)(gx + 2) < 1024u) s2 = srcr[gx + 2];
    }
    union { _Float16 h[2]; unsigned int u; } p0, p1;
    p0.h[0] = (_Float16)s0; p0.h[1] = (_Float16)s1;   // copy0: (e2d, e2d+1)
    p1.h[0] = (_Float16)s1; p1.h[1] = (_Float16)s2;   // copy1: (e2d+1, e2d+2)
    ldss[r * SROW + d]       = p0.u;
    ldss[r * SROW + SDW + d] = p1.u;
  }
  __syncthreads();

  const int lane = tid & 63;
  const int wv   = tid >> 6;
  const int n    = lane & 15;       // MFMA col -> x offset
  const int kg   = lane >> 4;       // k-group
  const int xw   = wv * 16;

  // per-lane fixed B-window base: elements E..E+7 of a row
  const int E = xw + n + 8 * kg;
  const unsigned int* lbase = ldss + (E & 1) * SDW + (E >> 1);

  f32x4 acc[8];
  #pragma unroll
  for (int p = 0; p < 8; ++p) acc[p] = (f32x4){0.f, 0.f, 0.f, 0.f};

  // B register cache: slot (row & 15); preload rows 0..15
  unsigned int Bc[16][4];
  #pragma unroll
  for (int r = 0; r < 16; ++r) {
    const unsigned int* q = lbase + r * SROW;
    Bc[r][0] = q[0]; Bc[r][1] = q[1]; Bc[r][2] = q[2]; Bc[r][3] = q[3];
  }

  const uint4* wq = (const uint4*)g_wA + (size_t)c * (32 * 64) + lane;
  uint4 aq = wq[0];

  for (int ib = 0; ib < 2; ++ib) {
    #pragma unroll
    for (int u = 0; u < 16; ++u) {
      const int i = ib * 16 + u;
      union { uint4 v; f16x8 h; } au;
      au.v = aq;
      if (i < 31) aq = wq[(i + 1) * 64];        // prefetch next A

      // p = 0 uses slot u (row i), then recycle slot u with row i+16
      {
        union { unsigned int uu[4]; f16x8 h; } b;
        b.uu[0] = Bc[u][0]; b.uu[1] = Bc[u][1]; b.uu[2] = Bc[u][2]; b.uu[3] = Bc[u][3];
        acc[0] = __builtin_amdgcn_mfma_f32_16x16x32_f16(au.h, b.h, acc[0], 0, 0, 0);
      }
      {
        const unsigned int* q = lbase + (i + 16) * SROW;   // rows 46/47 = garbage, never used
        Bc[u][0] = q[0]; Bc[u][1] = q[1]; Bc[u][2] = q[2]; Bc[u][3] = q[3];
      }
      #pragma unroll
      for (int p = 1; p < 8; ++p) {
        const int sl = (u + 2 * p) & 15;
        union { unsigned int uu[4]; f16x8 h; } b;
        b.uu[0] = Bc[sl][0]; b.uu[1] = Bc[sl][1]; b.uu[2] = Bc[sl][2]; b.uu[3] = Bc[sl][3];
        acc[p] = __builtin_amdgcn_mfma_f32_16x16x32_f16(au.h, b.h, acc[p], 0, 0, 0);
      }
    }
  }

  // ---- epilogue ----
  // D: col = lane&15 = n -> x; row m = 4kg + r = 8s + o -> s = kg>>1, o = (kg&1)*4 + r
  const float bv = bias[c];
  const int s   = kg >> 1;
  const int ob  = (kg & 1) * 4;
  const int xs  = x0 + xw + n;
  #pragma unroll
  for (int p = 0; p < 8; ++p) {
    const int y = y0 + 2 * p + s;
    #pragma unroll
    for (int r = 0; r < 4; ++r) {
      const int o = ob + r;
      out[(((size_t)(o * 8 + c) * 1024 + y) * 1024) + xs] = acc[p][r] + bv;
    }
  }
}

extern "C" void kernel_launch(void* const* d_in, const int* in_sizes, int n_in,
                              void* d_out, int out_size, void* d_ws, size_t ws_size,
                              hipStream_t stream) {
  const float* sig  = (const float*)d_in[0];   // (1,8,1024,1024) fp32
  const float* wgt  = (const float*)d_in[1];   // (8,8,31,31) fp32
  const float* bias = (const float*)d_in[2];   // (8,) fp32
  float* out = (float*)d_out;                  // (8,8,1024,1024) fp32

  wpack<<<(8 * 32 * 64 * 4 + 255) / 256, 256, 0, stream>>>(wgt);
  dim3 grid(1024 / TXB, 1024 / TY, 8);
  conv_mfma3<<<grid, 256, 0, stream>>>(sig, bias, out);
}